// Round 18
// baseline (223.580 us; speedup 1.0000x reference)
//
#include <hip/hip_runtime.h>

#define B_ 4
#define T_ 2048
#define C_ 1024
#define H_ 16
#define D_ 64
#define M_ (B_*T_)    // 8192
#define N3_ (3*C_)    // 3072
#define NQT_ 16       // number of 128-row q-tiles (= T/128)

typedef unsigned short u16;
typedef short bf16x8 __attribute__((ext_vector_type(8)));
typedef short bf16x4 __attribute__((ext_vector_type(4)));
typedef unsigned short u16x8 __attribute__((ext_vector_type(8)));
typedef unsigned int u32x4 __attribute__((ext_vector_type(4)));
typedef float f32x4 __attribute__((ext_vector_type(4)));
typedef float f32x16 __attribute__((ext_vector_type(16)));

#define QSCALE 0.18033688f   /* 0.125 * log2(e): softmax done in exp2 domain */
#define DEFER_THR 11.0f      /* defer-max threshold in log2 units (~8 nats) */

__device__ __forceinline__ u16 f2bf(float f) {
  unsigned u = __float_as_uint(f);
  u += 0x7fffu + ((u >> 16) & 1u);
  return (u16)(u >> 16);
}

__device__ __forceinline__ unsigned cvt_pk_bf16(float lo, float hi) {
  unsigned r;
  asm("v_cvt_pk_bf16_f32 %0, %1, %2" : "=v"(r) : "v"(lo), "v"(hi));
  return r;
}

__device__ __forceinline__ void gload16(const void* g, void* l) {
  __builtin_amdgcn_global_load_lds((const __attribute__((address_space(1))) void*)g,
                                   (__attribute__((address_space(3))) void*)l, 16, 0, 0);
}

// epilogue-tile swizzle key (R12-verified conflict-free on all paths)
__device__ __forceinline__ int epi_key(int ml) { return (ml ^ (ml >> 3)) & 7; }

// ---------------- fused prep: convert x, transpose weights, RoPE tables ----------
__global__ __launch_bounds__(256) void k_prep(const float* __restrict__ x,
                                              u16* __restrict__ xbf,
                                              const float* __restrict__ W_in,
                                              u16* __restrict__ WtIn,
                                              const float* __restrict__ W_out,
                                              u16* __restrict__ WtOut,
                                              float* __restrict__ ct,
                                              float* __restrict__ st) {
  __shared__ float tile[64][65];
  const int bx = blockIdx.x, tid = threadIdx.x;
  if (bx < 4096) {                       // x: f32 -> bf16, 8 elems/thread
    int i = bx * 256 + tid;
    f32x4 a = *(const f32x4*)(x + (size_t)i * 8);
    f32x4 b = *(const f32x4*)(x + (size_t)i * 8 + 4);
    u16x8 o;
    #pragma unroll
    for (int j = 0; j < 4; ++j) { o[j] = f2bf(a[j]); o[4 + j] = f2bf(b[j]); }
    *(u16x8*)(xbf + (size_t)i * 8) = o;
  } else if (bx < 5120) {                // weight transpose+convert
    const float* W; u16* Wt; int K = C_, N, b;
    if (bx < 4864) { W = W_in; Wt = WtIn; N = N3_; b = bx - 4096; }
    else           { W = W_out; Wt = WtOut; N = C_; b = bx - 4864; }
    int ntiles = N / 64;
    int n0 = (b % ntiles) * 64, k0 = (b / ntiles) * 64;
    int c = tid & 63, r0 = tid >> 6;
    #pragma unroll
    for (int i = 0; i < 16; ++i) {
      int r = i * 4 + r0;
      tile[r][c] = W[(size_t)(k0 + r) * N + n0 + c];
    }
    __syncthreads();
    #pragma unroll
    for (int i = 0; i < 16; ++i) {
      int r = i * 4 + r0;
      Wt[(size_t)(n0 + r) * K + k0 + c] = f2bf(tile[c][r]);
    }
  } else {                               // rope tables (double precision)
    int idx = (bx - 5120) * 256 + tid;   // T_*32 entries
    int t = idx >> 5, i = idx & 31;
    double inv = exp(-(2.0 * (double)i / 64.0) * log(10000.0));
    double a = (double)t * inv;
    ct[idx] = (float)cos(a);
    st[idx] = (float)sin(a);
  }
}

// ---------------- GEMM1: x @ W_in^T, 128M x 256N, 8 waves (R18) ----------------
// Bytes-law lever at >=2 blocks/CU: staged bytes/output 32->24B vs 128².
// 8 waves (per-wave 64x64, acc=64 VGPR) keeps VGPR ~104 and LDS 48KB single-
// buffered -> 2 blocks/CU (4 waves/SIMD; solo-tail still 2/SIMD, above the
// 1-wave/SIMD cliff that killed R14/R16). Same staging/swizzle as R12.
// Epilogue: two 128-wide halves through 32KB LDS tile; fused RoPE; Q/K rows
// and V columns (fused vtrans) copy out coalesced u16x8.
__global__ __launch_bounds__(512) void k_gemm1(const u16* __restrict__ A,
                                               const u16* __restrict__ Bt,
                                               const float* __restrict__ bias,
                                               u16* __restrict__ Qb, u16* __restrict__ Kb,
                                               u16* __restrict__ Vt,
                                               const float* __restrict__ ctab,
                                               const float* __restrict__ stab) {
  __shared__ u16 lds[128 * 64 + 256 * 64];   // sA 16KB + sB 32KB
  u16* sA = lds;
  u16* sB = lds + 128 * 64;
  const int tid = threadIdx.x, lane = tid & 63, w = tid >> 6;   // 8 waves
  const int g = lane >> 4, r = lane & 15;
  const int wm = w >> 2, wn = w & 3;                            // 2M x 4N
  const int Kd = C_;
  // XCD slab (8 M-rows per XCD), column-major within the slab. grid (12,64).
  const int lin = blockIdx.y * gridDim.x + blockIdx.x;
  const int tM = ((lin & 7) * 8 + ((lin >> 3) & 7)) * 128;
  const int tN = (lin >> 6) * 256;

  f32x4 acc[4][4];
  #pragma unroll
  for (int i = 0; i < 4; ++i)
    #pragma unroll
    for (int j = 0; j < 4; ++j) acc[i][j] = (f32x4){0.f, 0.f, 0.f, 0.f};

  for (int k0 = 0; k0 < Kd; k0 += 64) {
    #pragma unroll
    for (int i = 0; i < 2; ++i) {   // A: 128x64 = 1024 chunks
      int c = i * 512 + tid, row = c >> 3, slot = (c & 7) ^ (row & 7);
      gload16(A + (size_t)(tM + row) * Kd + k0 + slot * 8, sA + (i * 512 + w * 64) * 8);
    }
    #pragma unroll
    for (int i = 0; i < 4; ++i) {   // B: 256x64 = 2048 chunks
      int c = i * 512 + tid, row = c >> 3, slot = (c & 7) ^ (row & 7);
      gload16(Bt + (size_t)(tN + row) * Kd + k0 + slot * 8, sB + (i * 512 + w * 64) * 8);
    }
    __syncthreads();
    bf16x8 af[4][2], bfr[4][2];
    #pragma unroll
    for (int mt = 0; mt < 4; ++mt)
      #pragma unroll
      for (int kk = 0; kk < 2; ++kk) {
        int row = wm * 64 + mt * 16 + r;
        af[mt][kk] = *(const bf16x8*)(sA + ((row * 64 + kk * 32 + g * 8) ^ ((row & 7) << 3)));
      }
    #pragma unroll
    for (int nt = 0; nt < 4; ++nt)
      #pragma unroll
      for (int kk = 0; kk < 2; ++kk) {
        int row = wn * 64 + nt * 16 + r;
        bfr[nt][kk] = *(const bf16x8*)(sB + ((row * 64 + kk * 32 + g * 8) ^ ((row & 7) << 3)));
      }
    __builtin_amdgcn_s_setprio(1);
    #pragma unroll
    for (int mt = 0; mt < 4; ++mt)
      #pragma unroll
      for (int nt = 0; nt < 4; ++nt)
        #pragma unroll
        for (int kk = 0; kk < 2; ++kk)
          acc[mt][nt] = __builtin_amdgcn_mfma_f32_16x16x32_bf16(af[mt][kk], bfr[nt][kk],
                                                                acc[mt][nt], 0, 0, 0);
    __builtin_amdgcn_s_setprio(0);
    __syncthreads();
  }

  // epilogue: two 128-wide halves through 32KB tile (lds[0..16384))
  const int secb = tN >> 10;   // block-uniform: 256-tiles don't cross 1024
  u16* tile = lds;
  const int bb = tM >> 11;
  #pragma unroll
  for (int hN = 0; hN < 2; ++hN) {
    if ((wn >> 1) == hN) {     // waves owning this half write it (RoPE fused)
      #pragma unroll
      for (int mt = 0; mt < 4; ++mt)
        #pragma unroll
        for (int nt = 0; nt < 4; ++nt) {
          int nl = (wn & 1) * 64 + nt * 16 + r;     // 0..127 within half
          int n = tN + hN * 128 + nl;
          float bv = bias[n];
          int dd = n & 63;
          #pragma unroll
          for (int reg = 0; reg < 4; ++reg) {
            int ml = wm * 64 + mt * 16 + g * 4 + reg;
            int tt = (tM + ml) & (T_ - 1);
            float v = acc[mt][nt][reg] + bv;
            if (secb < 2) {   // fused RoPE on Q,K (pairs = adjacent lanes)
              float pv = __shfl_xor(v, 1);
              int pi = tt * 32 + (dd >> 1);
              float c = ctab[pi], sn = stab[pi];
              v = (dd & 1) ? (v * c + pv * sn) : (v * c - pv * sn);
              if (secb == 0) v *= QSCALE;
            }
            tile[ml * 128 + ((((nl >> 3) ^ epi_key(ml)) << 3) | (nl & 7))] = f2bf(v);
          }
        }
    }
    __syncthreads();
    if (secb < 2) {
      // rows -> Qb/Kb [B,H,T,D], coalesced u16x8 along d
      u16* dst = secb == 0 ? Qb : Kb;
      #pragma unroll
      for (int i = 0; i < 4; ++i) {
        int idx = i * 512 + tid;
        int row = idx >> 4, cc = idx & 15;
        u16x8 val = *(const u16x8*)(tile + row * 128 + ((cc ^ epi_key(row)) << 3));
        int n = tN + hN * 128 + cc * 8;
        int m = tM + row;
        int hh = (n & 1023) >> 6, dd = n & 63;
        int tt = m & (T_ - 1);
        *(u16x8*)(dst + ((size_t)(bb * H_ + hh) * T_ + tt) * D_ + dd) = val;
      }
    } else {
      // columns -> Vt [B,H,D,T], coalesced u16x8 along t (fused vtrans)
      const int tt0 = tM & (T_ - 1);
      #pragma unroll
      for (int i = 0; i < 4; ++i) {
        int idx = i * 512 + tid;
        int nl = idx >> 4, tg = idx & 15;
        u16x8 val;
        #pragma unroll
        for (int j = 0; j < 8; ++j) {
          int ml = tg * 8 + j;
          val[j] = tile[ml * 128 + ((((nl >> 3) ^ epi_key(ml)) << 3) | (nl & 7))];
        }
        int n = tN + hN * 128 + nl;
        int hh = (n & 1023) >> 6, dd = n & 63;
        *(u16x8*)(Vt + ((size_t)(bb * H_ + hh) * D_ + dd) * T_ + tt0 + tg * 8) = val;
      }
    }
    __syncthreads();
  }
}

// ---------------- GEMM2: y @ W_out^T -> fp32 out (R13 config, frozen) ----------
__global__ __launch_bounds__(256) void k_gemm2(const u16* __restrict__ A,
                                               const u16* __restrict__ Bt,
                                               const float* __restrict__ bias,
                                               float* __restrict__ Cout,
                                               int Nd, int Kd) {
  __shared__ u16 sA[128 * 128];   // 32KB
  __shared__ u16 sB[128 * 128];   // 32KB
  const int tid = threadIdx.x, lane = tid & 63, w = tid >> 6;
  const int g = lane >> 4, r = lane & 15;
  const int wm = w >> 1, wn = w & 1;
  const int lin = blockIdx.y * gridDim.x + blockIdx.x;
  const int tM = ((lin & 7) * 8 + ((lin >> 3) & 7)) * 128;
  const int tN = (lin >> 6) * 128;

  f32x4 acc[4][4];
  #pragma unroll
  for (int i = 0; i < 4; ++i)
    #pragma unroll
    for (int j = 0; j < 4; ++j) acc[i][j] = (f32x4){0.f, 0.f, 0.f, 0.f};

  for (int k0 = 0; k0 < Kd; k0 += 128) {
    #pragma unroll
    for (int i = 0; i < 8; ++i) {
      int c = i * 256 + tid, row = c >> 4, slot = (c & 15) ^ (row & 15);
      gload16(A + (size_t)(tM + row) * Kd + k0 + slot * 8, sA + (i * 256 + w * 64) * 8);
    }
    #pragma unroll
    for (int i = 0; i < 8; ++i) {
      int c = i * 256 + tid, row = c >> 4, slot = (c & 15) ^ (row & 15);
      gload16(Bt + (size_t)(tN + row) * Kd + k0 + slot * 8, sB + (i * 256 + w * 64) * 8);
    }
    __syncthreads();
    #pragma unroll
    for (int kk = 0; kk < 4; ++kk) {
      bf16x8 af[4], bfr[4];
      #pragma unroll
      for (int mt = 0; mt < 4; ++mt) {
        int row = wm * 64 + mt * 16 + r;
        af[mt] = *(const bf16x8*)(sA + row * 128 + (((kk * 4 + g) ^ (row & 15)) * 8));
      }
      #pragma unroll
      for (int nt = 0; nt < 4; ++nt) {
        int row = wn * 64 + nt * 16 + r;
        bfr[nt] = *(const bf16x8*)(sB + row * 128 + (((kk * 4 + g) ^ (row & 15)) * 8));
      }
      __builtin_amdgcn_s_setprio(1);
      #pragma unroll
      for (int mt = 0; mt < 4; ++mt)
        #pragma unroll
        for (int nt = 0; nt < 4; ++nt)
          acc[mt][nt] = __builtin_amdgcn_mfma_f32_16x16x32_bf16(af[mt], bfr[nt],
                                                                acc[mt][nt], 0, 0, 0);
      __builtin_amdgcn_s_setprio(0);
    }
    __syncthreads();
  }

  #pragma unroll
  for (int mt = 0; mt < 4; ++mt)
    #pragma unroll
    for (int nt = 0; nt < 4; ++nt) {
      int n = tN + wn * 64 + nt * 16 + r;
      float bv = bias[n];
      #pragma unroll
      for (int reg = 0; reg < 4; ++reg) {
        int m = tM + wm * 64 + mt * 16 + g * 4 + reg;
        Cout[(size_t)m * Nd + n] = acc[mt][nt][reg] + bv;   // coalesced f32
      }
    }
}

// ---------------- causal flash attention, 32x32 MFMA, causal-paired ----------------
// R15 config (best measured): 4 waves x 32 q = 128 q-rows/block; 512 blocks
// = 2/CU (R16 proved 1 block/CU is below the co-residency cliff).
__global__ __launch_bounds__(256) void k_attn(const u16* __restrict__ Qb,
                                              const u16* __restrict__ Kb,
                                              const u16* __restrict__ Vt,
                                              u16* __restrict__ Y) {
  __shared__ u16 sK[2][64 * 64];
  __shared__ u16 sV[2][64 * 64];
  const int tid = threadIdx.x, w = tid >> 6;          // 4 waves
  const int lane = tid & 63, col = lane & 31, hi = lane >> 5;
  const int pair = blockIdx.x;                        // 0..7
  const int h = blockIdx.y, b = blockIdx.z;
  const size_t bhK = ((size_t)b * H_ + h) * T_;
  const size_t bhV = ((size_t)b * H_ + h) * D_;

  const int qtA = pair, qtB = (NQT_ - 1) - pair;      // 128-row q-tiles
  const int ntA = 2 * qtA + 2;                        // KV tiles for half A
  const int total = 2 * (NQT_ - 1) + 4;               // = 34, uniform

  auto STAGE = [&](int buf, int kt) {
    #pragma unroll
    for (int i = 0; i < 2; ++i) {
      int c = i * 256 + tid, row = c >> 3, slot = (c & 7) ^ (row & 7);
      gload16(Kb + (bhK + kt * 64 + row) * D_ + slot * 8, &sK[buf][(i * 256 + w * 64) * 8]);
    }
    #pragma unroll
    for (int i = 0; i < 2; ++i) {
      int c = i * 256 + tid, row = c >> 3, slot = (c & 7) ^ (row & 7);
      gload16(Vt + (bhV + row) * T_ + kt * 64 + slot * 8, &sV[buf][(i * 256 + w * 64) * 8]);
    }
  };

  int qw = qtA * 128 + w * 32;
  int tq = qw + col;
  bf16x8 qf[4];
  #pragma unroll
  for (int c = 0; c < 4; ++c)
    qf[c] = *(const bf16x8*)(Qb + (bhK + tq) * D_ + c * 16 + hi * 8);

  float m_run = -3e38f, l_run = 0.f;
  f32x16 o0, o1;
  #pragma unroll
  for (int i = 0; i < 16; ++i) { o0[i] = 0.f; o1[i] = 0.f; }

  auto FINAL = [&]() {
    float lr = l_run + __shfl_xor(l_run, 32);
    float rl = 1.0f / lr;
    u16* yrow = Y + ((size_t)b * T_ + tq) * C_ + h * 64;
    #pragma unroll
    for (int dt = 0; dt < 2; ++dt)
      #pragma unroll
      for (int j = 0; j < 8; ++j) {
        float a0 = (dt ? o1[2 * j] : o0[2 * j]) * rl;
        float a1 = (dt ? o1[2 * j + 1] : o0[2 * j + 1]) * rl;
        int d = dt * 32 + 8 * (j >> 1) + 4 * hi + 2 * (j & 1);
        *(unsigned*)(yrow + d) = cvt_pk_bf16(a0, a1);
      }
  };

  STAGE(0, 0);
  __syncthreads();

  for (int it = 0; it < total; ++it) {
    const int cur = it & 1;
    if (it + 1 < total) {
      int nit = it + 1;
      STAGE(cur ^ 1, nit < ntA ? nit : nit - ntA);
    }
    const int ktl = it < ntA ? it : it - ntA;
    const int kb = ktl * 64;
    if (kb <= qw + 31) {
      const bool act1 = (kb + 32 <= qw + 31);
      f32x16 s0, s1;
      #pragma unroll
      for (int i = 0; i < 16; ++i) { s0[i] = 0.f; s1[i] = 0.f; }

      __builtin_amdgcn_s_setprio(1);
      #pragma unroll
      for (int c = 0; c < 4; ++c) {
        int row = col;
        bf16x8 kf = *(const bf16x8*)(&sK[cur][(row * 64 + c * 16 + hi * 8) ^ ((row & 7) << 3)]);
        s0 = __builtin_amdgcn_mfma_f32_32x32x16_bf16(kf, qf[c], s0, 0, 0, 0);
      }
      if (act1) {
        #pragma unroll
        for (int c = 0; c < 4; ++c) {
          int row = 32 + col;
          bf16x8 kf = *(const bf16x8*)(&sK[cur][(row * 64 + c * 16 + hi * 8) ^ ((row & 7) << 3)]);
          s1 = __builtin_amdgcn_mfma_f32_32x32x16_bf16(kf, qf[c], s1, 0, 0, 0);
        }
      }
      __builtin_amdgcn_s_setprio(0);

      if (kb + 31 > qw) {
        #pragma unroll
        for (int reg = 0; reg < 16; ++reg) {
          int key = kb + (reg & 3) + 8 * (reg >> 2) + 4 * hi;
          if (key > tq) s0[reg] = -3e38f;
        }
      }
      if (act1 && kb + 63 > qw) {
        #pragma unroll
        for (int reg = 0; reg < 16; ++reg) {
          int key = kb + 32 + (reg & 3) + 8 * (reg >> 2) + 4 * hi;
          if (key > tq) s1[reg] = -3e38f;
        }
      }

      float pm = s0[0];
      #pragma unroll
      for (int reg = 1; reg < 16; ++reg) pm = fmaxf(pm, s0[reg]);
      if (act1) {
        #pragma unroll
        for (int reg = 0; reg < 16; ++reg) pm = fmaxf(pm, s1[reg]);
      }
      if (__any(pm > m_run + DEFER_THR)) {
        float tm = fmaxf(pm, __shfl_xor(pm, 32));
        float mn = fmaxf(m_run, tm);
        float f = __builtin_amdgcn_exp2f(m_run - mn);
        m_run = mn;
        #pragma unroll
        for (int i = 0; i < 16; ++i) { o0[i] *= f; o1[i] *= f; }
        l_run *= f;
      }

      #pragma unroll
      for (int reg = 0; reg < 16; ++reg) {
        s0[reg] = __builtin_amdgcn_exp2f(s0[reg] - m_run);
        l_run += s0[reg];
      }
      if (act1) {
        #pragma unroll
        for (int reg = 0; reg < 16; ++reg) {
          s1[reg] = __builtin_amdgcn_exp2f(s1[reg] - m_run);
          l_run += s1[reg];
        }
      }

      __builtin_amdgcn_s_setprio(1);
      #pragma unroll
      for (int st = 0; st < 2; ++st) {
        if (st == 1 && !act1) break;
        #pragma unroll
        for (int u = 0; u < 2; ++u) {
          u32x4 pw;
          #pragma unroll
          for (int j = 0; j < 4; ++j) {
            int jr = (4 * u + j) * 2;
            pw[j] = st ? cvt_pk_bf16(s1[jr], s1[jr + 1])
                       : cvt_pk_bf16(s0[jr], s0[jr + 1]);
          }
          bf16x8 pf = __builtin_bit_cast(bf16x8, pw);
          const int keybase = st * 32 + u * 16;
          #pragma unroll
          for (int dt = 0; dt < 2; ++dt) {
            int row = dt * 32 + col;
            int e0 = (row * 64 + keybase + 4 * hi) ^ ((row & 7) << 3);
            int e1 = (row * 64 + keybase + 8 + 4 * hi) ^ ((row & 7) << 3);
            bf16x4 vlo = *(const bf16x4*)(&sV[cur][e0]);
            bf16x4 vhi = *(const bf16x4*)(&sV[cur][e1]);
            bf16x8 vf;
            vf[0] = vlo[0]; vf[1] = vlo[1]; vf[2] = vlo[2]; vf[3] = vlo[3];
            vf[4] = vhi[0]; vf[5] = vhi[1]; vf[6] = vhi[2]; vf[7] = vhi[3];
            if (dt == 0) o0 = __builtin_amdgcn_mfma_f32_32x32x16_bf16(vf, pf, o0, 0, 0, 0);
            else         o1 = __builtin_amdgcn_mfma_f32_32x32x16_bf16(vf, pf, o1, 0, 0, 0);
          }
        }
      }
      __builtin_amdgcn_s_setprio(0);
    }
    __syncthreads();

    if (it == ntA - 1) {
      FINAL();
      qw = qtB * 128 + w * 32;
      tq = qw + col;
      #pragma unroll
      for (int c = 0; c < 4; ++c)
        qf[c] = *(const bf16x8*)(Qb + (bhK + tq) * D_ + c * 16 + hi * 8);
      m_run = -3e38f; l_run = 0.f;
      #pragma unroll
      for (int i = 0; i < 16; ++i) { o0[i] = 0.f; o1[i] = 0.f; }
    }
  }
  FINAL();
}

extern "C" void kernel_launch(void* const* d_in, const int* in_sizes, int n_in,
                              void* d_out, int out_size, void* d_ws, size_t ws_size,
                              hipStream_t stream) {
  const float* x     = (const float*)d_in[0];
  const float* W_in  = (const float*)d_in[1];
  const float* b_in  = (const float*)d_in[2];
  const float* W_out = (const float*)d_in[3];
  const float* b_out = (const float*)d_in[4];
  float* out = (float*)d_out;

  const size_t NE = (size_t)B_ * H_ * T_ * D_;   // 8388608
  u16* Qb    = (u16*)d_ws;
  u16* Kb    = Qb + NE;
  u16* Vt    = Kb + NE;     // [B,H,D,T], written directly by GEMM1 epilogue
  u16* xbf   = Vt + NE;     // GEMM1 A-input; becomes ybf after GEMM1
  u16* WtIn  = xbf + (size_t)M_ * C_;
  u16* WtOut = WtIn + (size_t)N3_ * C_;
  float* ctab = (float*)(WtOut + (size_t)C_ * C_);
  float* stab = ctab + T_ * 32;
  u16* ybf = xbf;   // overlays xbf (dead after GEMM1)

  size_t needed = (size_t)((char*)(stab + T_ * 32) - (char*)d_ws);
  if (ws_size < needed) return;

  k_prep<<<5376, 256, 0, stream>>>(x, xbf, W_in, WtIn, W_out, WtOut, ctab, stab);

  k_gemm1<<<dim3(N3_ / 256, M_ / 128), 512, 0, stream>>>(
      xbf, WtIn, b_in, Qb, Kb, Vt, ctab, stab);

  k_attn<<<dim3(NQT_ / 2, H_, B_), 256, 0, stream>>>(Qb, Kb, Vt, ybf);

  k_gemm2<<<dim3(C_ / 128, M_ / 128), 256, 0, stream>>>(
      ybf, WtOut, b_out, out, C_, C_);
}

// Round 19
// 183.919 us; speedup vs baseline: 1.2156x; 1.2156x over previous
//
#include <hip/hip_runtime.h>

#define B_ 4
#define T_ 2048
#define C_ 1024
#define H_ 16
#define D_ 64
#define M_ (B_*T_)    // 8192
#define N3_ (3*C_)    // 3072
#define NQT_ 16       // number of 128-row q-tiles (= T/128)

typedef unsigned short u16;
typedef short bf16x8 __attribute__((ext_vector_type(8)));
typedef short bf16x4 __attribute__((ext_vector_type(4)));
typedef unsigned short u16x8 __attribute__((ext_vector_type(8)));
typedef unsigned int u32x4 __attribute__((ext_vector_type(4)));
typedef float f32x4 __attribute__((ext_vector_type(4)));
typedef float f32x16 __attribute__((ext_vector_type(16)));

#define QSCALE 0.18033688f   /* 0.125 * log2(e): softmax done in exp2 domain */
#define DEFER_THR 11.0f      /* defer-max threshold in log2 units (~8 nats) */

__device__ __forceinline__ u16 f2bf(float f) {
  unsigned u = __float_as_uint(f);
  u += 0x7fffu + ((u >> 16) & 1u);
  return (u16)(u >> 16);
}

__device__ __forceinline__ unsigned cvt_pk_bf16(float lo, float hi) {
  unsigned r;
  asm("v_cvt_pk_bf16_f32 %0, %1, %2" : "=v"(r) : "v"(lo), "v"(hi));
  return r;
}

__device__ __forceinline__ void gload16(const void* g, void* l) {
  __builtin_amdgcn_global_load_lds((const __attribute__((address_space(1))) void*)g,
                                   (__attribute__((address_space(3))) void*)l, 16, 0, 0);
}

// epilogue-tile swizzle key (R12-verified conflict-free on all paths)
__device__ __forceinline__ int epi_key(int ml) { return (ml ^ (ml >> 3)) & 7; }

// ---------------- fused prep: convert x, transpose weights, RoPE tables ----------
__global__ __launch_bounds__(256) void k_prep(const float* __restrict__ x,
                                              u16* __restrict__ xbf,
                                              const float* __restrict__ W_in,
                                              u16* __restrict__ WtIn,
                                              const float* __restrict__ W_out,
                                              u16* __restrict__ WtOut,
                                              float* __restrict__ ct,
                                              float* __restrict__ st) {
  __shared__ float tile[64][65];
  const int bx = blockIdx.x, tid = threadIdx.x;
  if (bx < 4096) {                       // x: f32 -> bf16, 8 elems/thread
    int i = bx * 256 + tid;
    f32x4 a = *(const f32x4*)(x + (size_t)i * 8);
    f32x4 b = *(const f32x4*)(x + (size_t)i * 8 + 4);
    u16x8 o;
    #pragma unroll
    for (int j = 0; j < 4; ++j) { o[j] = f2bf(a[j]); o[4 + j] = f2bf(b[j]); }
    *(u16x8*)(xbf + (size_t)i * 8) = o;
  } else if (bx < 5120) {                // weight transpose+convert
    const float* W; u16* Wt; int K = C_, N, b;
    if (bx < 4864) { W = W_in; Wt = WtIn; N = N3_; b = bx - 4096; }
    else           { W = W_out; Wt = WtOut; N = C_; b = bx - 4864; }
    int ntiles = N / 64;
    int n0 = (b % ntiles) * 64, k0 = (b / ntiles) * 64;
    int c = tid & 63, r0 = tid >> 6;
    #pragma unroll
    for (int i = 0; i < 16; ++i) {
      int r = i * 4 + r0;
      tile[r][c] = W[(size_t)(k0 + r) * N + n0 + c];
    }
    __syncthreads();
    #pragma unroll
    for (int i = 0; i < 16; ++i) {
      int r = i * 4 + r0;
      Wt[(size_t)(n0 + r) * K + k0 + c] = f2bf(tile[c][r]);
    }
  } else {                               // rope tables (double precision)
    int idx = (bx - 5120) * 256 + tid;   // T_*32 entries
    int t = idx >> 5, i = idx & 31;
    double inv = exp(-(2.0 * (double)i / 64.0) * log(10000.0));
    double a = (double)t * inv;
    ct[idx] = (float)cos(a);
    st[idx] = (float)sin(a);
  }
}

// ---------------- bf16 GEMM: A[M][K] @ Bt[N][K]^T + bias ----------------
// R13 config (best measured; GEMM frozen after 7 failed restructures:
// dbuf R6, counted-vmcnt R7, 8-phase R8, reg-stage R11, 256x128 R14,
// 128x256 R18, BK sweep R13). 128x128 tile, BK=128, 4 waves, single-
// buffered, 64KB LDS (2 blocks/CU). XCD M-slab column-major ordering
// keeps A-slab L2-resident.
// MODE 0 epilogue: tile in LDS (RoPE fused), epi_key swizzle; Q/K rows and
// V columns (fused vtrans) copy out coalesced u16x8.  MODE 1: fp32 C.
template <int MODE>
__global__ __launch_bounds__(256) void k_gemm(const u16* __restrict__ A,
                                              const u16* __restrict__ Bt,
                                              const float* __restrict__ bias,
                                              float* __restrict__ Cout,
                                              u16* __restrict__ Qb, u16* __restrict__ Kb,
                                              u16* __restrict__ Vt,
                                              const float* __restrict__ ctab,
                                              const float* __restrict__ stab,
                                              int Md, int Nd, int Kd) {
  __shared__ u16 sA[128 * 128];   // 32KB
  __shared__ u16 sB[128 * 128];   // 32KB
  const int tid = threadIdx.x, lane = tid & 63, w = tid >> 6;
  const int g = lane >> 4, r = lane & 15;
  const int wm = w >> 1, wn = w & 1;
  // XCD slab (8 M-rows per XCD), column-major within the slab.
  const int lin = blockIdx.y * gridDim.x + blockIdx.x;
  const int tM = ((lin & 7) * 8 + ((lin >> 3) & 7)) * 128;
  const int tN = (lin >> 6) * 128;

  f32x4 acc[4][4];
  #pragma unroll
  for (int i = 0; i < 4; ++i)
    #pragma unroll
    for (int j = 0; j < 4; ++j) acc[i][j] = (f32x4){0.f, 0.f, 0.f, 0.f};

  for (int k0 = 0; k0 < Kd; k0 += 128) {
    #pragma unroll
    for (int i = 0; i < 8; ++i) {
      int c = i * 256 + tid, row = c >> 4, slot = (c & 15) ^ (row & 15);
      gload16(A + (size_t)(tM + row) * Kd + k0 + slot * 8, sA + (i * 256 + w * 64) * 8);
    }
    #pragma unroll
    for (int i = 0; i < 8; ++i) {
      int c = i * 256 + tid, row = c >> 4, slot = (c & 15) ^ (row & 15);
      gload16(Bt + (size_t)(tN + row) * Kd + k0 + slot * 8, sB + (i * 256 + w * 64) * 8);
    }
    __syncthreads();
    #pragma unroll
    for (int kk = 0; kk < 4; ++kk) {
      bf16x8 af[4], bfr[4];
      #pragma unroll
      for (int mt = 0; mt < 4; ++mt) {
        int row = wm * 64 + mt * 16 + r;
        af[mt] = *(const bf16x8*)(sA + row * 128 + (((kk * 4 + g) ^ (row & 15)) * 8));
      }
      #pragma unroll
      for (int nt = 0; nt < 4; ++nt) {
        int row = wn * 64 + nt * 16 + r;
        bfr[nt] = *(const bf16x8*)(sB + row * 128 + (((kk * 4 + g) ^ (row & 15)) * 8));
      }
      __builtin_amdgcn_s_setprio(1);
      #pragma unroll
      for (int mt = 0; mt < 4; ++mt)
        #pragma unroll
        for (int nt = 0; nt < 4; ++nt)
          acc[mt][nt] = __builtin_amdgcn_mfma_f32_16x16x32_bf16(af[mt], bfr[nt],
                                                                acc[mt][nt], 0, 0, 0);
      __builtin_amdgcn_s_setprio(0);
    }
    __syncthreads();
  }

  // epilogue: C/D layout col = lane&15, row = (lane>>4)*4 + reg
  if (MODE == 1) {
    #pragma unroll
    for (int mt = 0; mt < 4; ++mt)
      #pragma unroll
      for (int nt = 0; nt < 4; ++nt) {
        int n = tN + wn * 64 + nt * 16 + r;
        float bv = bias[n];
        #pragma unroll
        for (int reg = 0; reg < 4; ++reg) {
          int m = tM + wm * 64 + mt * 16 + g * 4 + reg;
          Cout[(size_t)m * Nd + n] = acc[mt][nt][reg] + bv;   // coalesced f32
        }
      }
  } else {
    // stage tile (bias + RoPE applied) in LDS; epi_key swizzle
    const int secb = tN >> 10;
    u16* tile = sA;   // [128][128] u16 (reuses staging LDS)
    #pragma unroll
    for (int mt = 0; mt < 4; ++mt)
      #pragma unroll
      for (int nt = 0; nt < 4; ++nt) {
        int nl = wn * 64 + nt * 16 + r;
        int n = tN + nl;
        float bv = bias[n];
        int dd = n & 63;
        #pragma unroll
        for (int reg = 0; reg < 4; ++reg) {
          int ml = wm * 64 + mt * 16 + g * 4 + reg;
          int tt = (tM + ml) & (T_ - 1);
          float v = acc[mt][nt][reg] + bv;
          if (secb < 2) {   // fused RoPE on Q,K (pairs = adjacent lanes, DPP)
            float pv = __shfl_xor(v, 1);
            int pi = tt * 32 + (dd >> 1);
            float c = ctab[pi], sn = stab[pi];
            v = (dd & 1) ? (v * c + pv * sn) : (v * c - pv * sn);
            if (secb == 0) v *= QSCALE;
          }
          tile[ml * 128 + ((((nl >> 3) ^ epi_key(ml)) << 3) | (nl & 7))] = f2bf(v);
        }
      }
    __syncthreads();
    if (secb < 2) {
      // rows -> Qb/Kb [B,H,T,D], coalesced u16x8 along d
      u16* dst = secb == 0 ? Qb : Kb;
      #pragma unroll
      for (int i = 0; i < 8; ++i) {
        int row = w * 32 + (i & 3) * 8 + (lane >> 3);
        int cc = (i >> 2) * 8 + (lane & 7);
        u16x8 val = *(const u16x8*)(tile + row * 128 + ((cc ^ epi_key(row)) << 3));
        int n = tN + cc * 8;
        int m = tM + row;
        int hh = (n & 1023) >> 6, dd = n & 63;
        int bb = m >> 11, tt = m & (T_ - 1);
        *(u16x8*)(dst + ((size_t)(bb * H_ + hh) * T_ + tt) * D_ + dd) = val;
      }
    } else {
      // columns -> Vt [B,H,D,T], coalesced u16x8 along t (fused k_vtrans)
      const int bb = tM >> 11, tt0 = tM & (T_ - 1);
      #pragma unroll
      for (int v = 0; v < 8; ++v) {
        int idx = v * 256 + tid;
        int nl = idx >> 4;          // 0..127 (d-column)
        int tg = idx & 15;          // t-group of 8
        u16x8 val;
        #pragma unroll
        for (int j = 0; j < 8; ++j) {
          int ml = tg * 8 + j;
          val[j] = tile[ml * 128 + ((((nl >> 3) ^ epi_key(ml)) << 3) | (nl & 7))];
        }
        int n = tN + nl;
        int hh = (n & 1023) >> 6, dd = n & 63;
        *(u16x8*)(Vt + ((size_t)(bb * H_ + hh) * D_ + dd) * T_ + tt0 + tg * 8) = val;
      }
    }
  }
}

// ---------------- causal flash attention, 32x32 MFMA, causal-paired ----------------
// R15 config (best measured): 4 waves x 32 q = 128 q-rows/block; K/V staged
// once per block (staging-bytes-bound). Pairing over 16 q-tiles of 128:
// qtA=pair, qtB=15-pair -> uniform 34 KV-iters; 512 blocks = 2/CU (R16
// proved 1 block/CU is below the co-residency cliff: 31->131us).
__global__ __launch_bounds__(256) void k_attn(const u16* __restrict__ Qb,
                                              const u16* __restrict__ Kb,
                                              const u16* __restrict__ Vt,
                                              u16* __restrict__ Y) {
  __shared__ u16 sK[2][64 * 64];
  __shared__ u16 sV[2][64 * 64];
  const int tid = threadIdx.x, w = tid >> 6;          // 4 waves
  const int lane = tid & 63, col = lane & 31, hi = lane >> 5;
  const int pair = blockIdx.x;                        // 0..7
  const int h = blockIdx.y, b = blockIdx.z;
  const size_t bhK = ((size_t)b * H_ + h) * T_;
  const size_t bhV = ((size_t)b * H_ + h) * D_;

  const int qtA = pair, qtB = (NQT_ - 1) - pair;      // 128-row q-tiles
  const int ntA = 2 * qtA + 2;                        // KV tiles for half A
  const int total = 2 * (NQT_ - 1) + 4;               // = 34, uniform

  auto STAGE = [&](int buf, int kt) {
    #pragma unroll
    for (int i = 0; i < 2; ++i) {
      int c = i * 256 + tid, row = c >> 3, slot = (c & 7) ^ (row & 7);
      gload16(Kb + (bhK + kt * 64 + row) * D_ + slot * 8, &sK[buf][(i * 256 + w * 64) * 8]);
    }
    #pragma unroll
    for (int i = 0; i < 2; ++i) {
      int c = i * 256 + tid, row = c >> 3, slot = (c & 7) ^ (row & 7);
      gload16(Vt + (bhV + row) * T_ + kt * 64 + slot * 8, &sV[buf][(i * 256 + w * 64) * 8]);
    }
  };

  int qw = qtA * 128 + w * 32;
  int tq = qw + col;
  bf16x8 qf[4];
  #pragma unroll
  for (int c = 0; c < 4; ++c)
    qf[c] = *(const bf16x8*)(Qb + (bhK + tq) * D_ + c * 16 + hi * 8);

  float m_run = -3e38f, l_run = 0.f;
  f32x16 o0, o1;
  #pragma unroll
  for (int i = 0; i < 16; ++i) { o0[i] = 0.f; o1[i] = 0.f; }

  auto FINAL = [&]() {
    float lr = l_run + __shfl_xor(l_run, 32);
    float rl = 1.0f / lr;
    u16* yrow = Y + ((size_t)b * T_ + tq) * C_ + h * 64;
    #pragma unroll
    for (int dt = 0; dt < 2; ++dt)
      #pragma unroll
      for (int j = 0; j < 8; ++j) {
        float a0 = (dt ? o1[2 * j] : o0[2 * j]) * rl;
        float a1 = (dt ? o1[2 * j + 1] : o0[2 * j + 1]) * rl;
        int d = dt * 32 + 8 * (j >> 1) + 4 * hi + 2 * (j & 1);
        *(unsigned*)(yrow + d) = cvt_pk_bf16(a0, a1);
      }
  };

  STAGE(0, 0);
  __syncthreads();

  for (int it = 0; it < total; ++it) {
    const int cur = it & 1;
    if (it + 1 < total) {
      int nit = it + 1;
      STAGE(cur ^ 1, nit < ntA ? nit : nit - ntA);
    }
    const int ktl = it < ntA ? it : it - ntA;
    const int kb = ktl * 64;
    if (kb <= qw + 31) {
      const bool act1 = (kb + 32 <= qw + 31);
      f32x16 s0, s1;
      #pragma unroll
      for (int i = 0; i < 16; ++i) { s0[i] = 0.f; s1[i] = 0.f; }

      __builtin_amdgcn_s_setprio(1);
      #pragma unroll
      for (int c = 0; c < 4; ++c) {
        int row = col;
        bf16x8 kf = *(const bf16x8*)(&sK[cur][(row * 64 + c * 16 + hi * 8) ^ ((row & 7) << 3)]);
        s0 = __builtin_amdgcn_mfma_f32_32x32x16_bf16(kf, qf[c], s0, 0, 0, 0);
      }
      if (act1) {
        #pragma unroll
        for (int c = 0; c < 4; ++c) {
          int row = 32 + col;
          bf16x8 kf = *(const bf16x8*)(&sK[cur][(row * 64 + c * 16 + hi * 8) ^ ((row & 7) << 3)]);
          s1 = __builtin_amdgcn_mfma_f32_32x32x16_bf16(kf, qf[c], s1, 0, 0, 0);
        }
      }
      __builtin_amdgcn_s_setprio(0);

      if (kb + 31 > qw) {
        #pragma unroll
        for (int reg = 0; reg < 16; ++reg) {
          int key = kb + (reg & 3) + 8 * (reg >> 2) + 4 * hi;
          if (key > tq) s0[reg] = -3e38f;
        }
      }
      if (act1 && kb + 63 > qw) {
        #pragma unroll
        for (int reg = 0; reg < 16; ++reg) {
          int key = kb + 32 + (reg & 3) + 8 * (reg >> 2) + 4 * hi;
          if (key > tq) s1[reg] = -3e38f;
        }
      }

      float pm = s0[0];
      #pragma unroll
      for (int reg = 1; reg < 16; ++reg) pm = fmaxf(pm, s0[reg]);
      if (act1) {
        #pragma unroll
        for (int reg = 0; reg < 16; ++reg) pm = fmaxf(pm, s1[reg]);
      }
      if (__any(pm > m_run + DEFER_THR)) {
        float tm = fmaxf(pm, __shfl_xor(pm, 32));
        float mn = fmaxf(m_run, tm);
        float f = __builtin_amdgcn_exp2f(m_run - mn);
        m_run = mn;
        #pragma unroll
        for (int i = 0; i < 16; ++i) { o0[i] *= f; o1[i] *= f; }
        l_run *= f;
      }

      #pragma unroll
      for (int reg = 0; reg < 16; ++reg) {
        s0[reg] = __builtin_amdgcn_exp2f(s0[reg] - m_run);
        l_run += s0[reg];
      }
      if (act1) {
        #pragma unroll
        for (int reg = 0; reg < 16; ++reg) {
          s1[reg] = __builtin_amdgcn_exp2f(s1[reg] - m_run);
          l_run += s1[reg];
        }
      }

      __builtin_amdgcn_s_setprio(1);
      #pragma unroll
      for (int st = 0; st < 2; ++st) {
        if (st == 1 && !act1) break;
        #pragma unroll
        for (int u = 0; u < 2; ++u) {
          u32x4 pw;
          #pragma unroll
          for (int j = 0; j < 4; ++j) {
            int jr = (4 * u + j) * 2;
            pw[j] = st ? cvt_pk_bf16(s1[jr], s1[jr + 1])
                       : cvt_pk_bf16(s0[jr], s0[jr + 1]);
          }
          bf16x8 pf = __builtin_bit_cast(bf16x8, pw);
          const int keybase = st * 32 + u * 16;
          #pragma unroll
          for (int dt = 0; dt < 2; ++dt) {
            int row = dt * 32 + col;
            int e0 = (row * 64 + keybase + 4 * hi) ^ ((row & 7) << 3);
            int e1 = (row * 64 + keybase + 8 + 4 * hi) ^ ((row & 7) << 3);
            bf16x4 vlo = *(const bf16x4*)(&sV[cur][e0]);
            bf16x4 vhi = *(const bf16x4*)(&sV[cur][e1]);
            bf16x8 vf;
            vf[0] = vlo[0]; vf[1] = vlo[1]; vf[2] = vlo[2]; vf[3] = vlo[3];
            vf[4] = vhi[0]; vf[5] = vhi[1]; vf[6] = vhi[2]; vf[7] = vhi[3];
            if (dt == 0) o0 = __builtin_amdgcn_mfma_f32_32x32x16_bf16(vf, pf, o0, 0, 0, 0);
            else         o1 = __builtin_amdgcn_mfma_f32_32x32x16_bf16(vf, pf, o1, 0, 0, 0);
          }
        }
      }
      __builtin_amdgcn_s_setprio(0);
    }
    __syncthreads();

    if (it == ntA - 1) {
      FINAL();
      qw = qtB * 128 + w * 32;
      tq = qw + col;
      #pragma unroll
      for (int c = 0; c < 4; ++c)
        qf[c] = *(const bf16x8*)(Qb + (bhK + tq) * D_ + c * 16 + hi * 8);
      m_run = -3e38f; l_run = 0.f;
      #pragma unroll
      for (int i = 0; i < 16; ++i) { o0[i] = 0.f; o1[i] = 0.f; }
    }
  }
  FINAL();
}

extern "C" void kernel_launch(void* const* d_in, const int* in_sizes, int n_in,
                              void* d_out, int out_size, void* d_ws, size_t ws_size,
                              hipStream_t stream) {
  const float* x     = (const float*)d_in[0];
  const float* W_in  = (const float*)d_in[1];
  const float* b_in  = (const float*)d_in[2];
  const float* W_out = (const float*)d_in[3];
  const float* b_out = (const float*)d_in[4];
  float* out = (float*)d_out;

  const size_t NE = (size_t)B_ * H_ * T_ * D_;   // 8388608
  u16* Qb    = (u16*)d_ws;
  u16* Kb    = Qb + NE;
  u16* Vt    = Kb + NE;     // [B,H,D,T], written directly by GEMM1 epilogue
  u16* xbf   = Vt + NE;     // GEMM1 A-input; becomes ybf after GEMM1
  u16* WtIn  = xbf + (size_t)M_ * C_;
  u16* WtOut = WtIn + (size_t)N3_ * C_;
  float* ctab = (float*)(WtOut + (size_t)C_ * C_);
  float* stab = ctab + T_ * 32;
  u16* ybf = xbf;   // overlays xbf (dead after GEMM1)

  size_t needed = (size_t)((char*)(stab + T_ * 32) - (char*)d_ws);
  if (ws_size < needed) return;

  k_prep<<<5376, 256, 0, stream>>>(x, xbf, W_in, WtIn, W_out, WtOut, ctab, stab);

  k_gemm<0><<<dim3(N3_ / 128, M_ / 128), 256, 0, stream>>>(
      xbf, WtIn, b_in, nullptr, Qb, Kb, Vt, ctab, stab, M_, N3_, C_);

  k_attn<<<dim3(NQT_ / 2, H_, B_), 256, 0, stream>>>(Qb, Kb, Vt, ybf);

  k_gemm<1><<<dim3(C_ / 128, M_ / 128), 256, 0, stream>>>(
      ybf, WtOut, b_out, out, nullptr, nullptr, nullptr, nullptr, nullptr, M_, C_, C_);
}